// Round 2
// baseline (480.466 us; speedup 1.0000x reference)
//
#include <hip/hip_runtime.h>
#include <math.h>

#define N_TOKENS 32768
#define DIM      4096
#define NE       64
#define TM       64      // tokens per block
#define BK       64      // K-chunk
#define PAD      68      // LDS row stride (floats)
#define NBLK     (N_TOKENS / TM)   // 512 blocks
#define EPS_GAP  2e-3f
#define REFINE_BLOCKS 1024

// d_out layout (float32 elements):
//   [0, 65536)        weights  [N_TOKENS][2]
//   [65536, 131072)   indices  [N_TOKENS][2]  stored as float
//   [131072, 131136)  new_bias [64]
//
// d_ws layout (4-byte elements):
//   [0, 64)              ews_refine[64]  (float, zeroed per call)
//   [64]                 worklist count  (uint, zeroed per call)
//   [128, 128+32768)     per-block expert partials [NBLK][NE] (float)
//   [32896, 65664)       worklist token ids (int)

__global__ __launch_bounds__(256) void gate_main(
    const float* __restrict__ x,      // [N_TOKENS][DIM]
    const float* __restrict__ w,      // [NE][DIM]
    const float* __restrict__ bias,   // [NE]
    float* __restrict__ out,
    float* __restrict__ ws)
{
    __shared__ float xs[BK][PAD];   // transposed: xs[k][token]
    __shared__ float wsh[BK][PAD];  // transposed: wsh[k][expert]
    __shared__ float part[NE];
    __shared__ float sbias[NE];

    unsigned* wl_count = (unsigned*)(ws + 64);
    float*    partials = ws + 128;
    int*      wl       = (int*)(ws + 128 + NBLK * NE);

    const int t  = threadIdx.x;          // 0..255
    const int tb = blockIdx.x * TM;      // token base
    const int tr = t >> 4;               // token group (4 tokens)
    const int tc = t & 15;               // expert group (4 experts)

    if (t < NE) { sbias[t] = bias[t]; part[t] = 0.f; }

    const int lq   = t & 15;             // k-quad for staging
    const int lrow = t >> 4;             // row low index for staging

    float acc[4][4];
    #pragma unroll
    for (int i = 0; i < 4; ++i)
        #pragma unroll
        for (int j = 0; j < 4; ++j) acc[i][j] = 0.f;

    for (int kc = 0; kc < DIM; kc += BK) {
        #pragma unroll
        for (int j = 0; j < 4; ++j) {
            const int row = j * 16 + lrow;           // 0..63
            const float4 vx = *(const float4*)(x + (size_t)(tb + row) * DIM + kc + lq * 4);
            const float4 vw = *(const float4*)(w + (size_t)row * DIM + kc + lq * 4);
            xs [lq*4+0][row] = vx.x; xs [lq*4+1][row] = vx.y;
            xs [lq*4+2][row] = vx.z; xs [lq*4+3][row] = vx.w;
            wsh[lq*4+0][row] = vw.x; wsh[lq*4+1][row] = vw.y;
            wsh[lq*4+2][row] = vw.z; wsh[lq*4+3][row] = vw.w;
        }
        __syncthreads();

        #pragma unroll 8
        for (int k = 0; k < BK; ++k) {
            const float4 a = *(const float4*)&xs [k][tr * 4];
            const float4 b = *(const float4*)&wsh[k][tc * 4];
            acc[0][0] += a.x * b.x; acc[0][1] += a.x * b.y; acc[0][2] += a.x * b.z; acc[0][3] += a.x * b.w;
            acc[1][0] += a.y * b.x; acc[1][1] += a.y * b.y; acc[1][2] += a.y * b.z; acc[1][3] += a.y * b.w;
            acc[2][0] += a.z * b.x; acc[2][1] += a.z * b.y; acc[2][2] += a.z * b.z; acc[2][3] += a.z * b.w;
            acc[3][0] += a.w * b.x; acc[3][1] += a.w * b.y; acc[3][2] += a.w * b.z; acc[3][3] += a.w * b.w;
        }
        __syncthreads();
    }

    // scores -> LDS (reuse xs as sc[token][expert])
    #pragma unroll
    for (int i = 0; i < 4; ++i) {
        float4 v;
        v.x = acc[i][0]; v.y = acc[i][1]; v.z = acc[i][2]; v.w = acc[i][3];
        *(float4*)&xs[tr * 4 + i][tc * 4] = v;
    }
    __syncthreads();

    if (t < TM) {
        const int tok = t;
        float v1 = -3e38f, v2 = -3e38f, v3 = -3e38f;
        int   i1 = 0,      i2 = 0;
        #pragma unroll 8
        for (int e = 0; e < NE; ++e) {
            const float s = xs[tok][e] + sbias[e];
            if (s > v1)      { v3 = v2; v2 = v1; i2 = i1; v1 = s; i1 = e; }
            else if (s > v2) { v3 = v2; v2 = s;  i2 = e; }
            else if (s > v3) { v3 = s; }
        }
        const bool risky = (v1 - v2 < EPS_GAP) || (v2 - v3 < EPS_GAP);
        if (risky) {
            const int pos = (int)atomicAdd(wl_count, 1u);
            wl[pos] = tb + tok;                  // refined later in fp64
        } else {
            const float ex = expf(v2 - v1);      // <= 1
            const float w1 = 1.f / (1.f + ex);
            const float w2 = ex * w1;
            const size_t g = (size_t)(tb + tok) * 2;
            *(float2*)(out + g)                        = make_float2(w1, w2);
            *(float2*)(out + (size_t)N_TOKENS * 2 + g) = make_float2((float)i1, (float)i2);
            atomicAdd(&part[i1], w1);
            atomicAdd(&part[i2], w2);
        }
    }
    __syncthreads();

    if (t < NE) partials[(size_t)blockIdx.x * NE + t] = part[t];
}

// fp64 re-score of near-tie tokens: exact ordering vs the true scores.
__global__ __launch_bounds__(256) void gate_refine(
    const float* __restrict__ x,
    const float* __restrict__ w,
    const float* __restrict__ bias,
    float* __restrict__ out,
    float* __restrict__ ws)
{
    float*          ews_ref  = ws;
    const unsigned* wl_count = (const unsigned*)(ws + 64);
    const int*      wl       = (const int*)(ws + 128 + NBLK * NE);

    const int t = threadIdx.x;
    const int e = t >> 2;        // expert 0..63
    const int q = t & 3;         // quarter of K
    __shared__ double sc[NE];

    const unsigned count = *wl_count;
    for (unsigned it = blockIdx.x; it < count; it += gridDim.x) {
        const int tok = wl[it];
        const float* xr = x + (size_t)tok * DIM;
        const float* wr = w + (size_t)e * DIM;
        double s = 0.0;
        const int k0 = q * (DIM / 4), k1 = k0 + DIM / 4;
        for (int k = k0; k < k1; k += 4) {
            const float4 a = *(const float4*)(xr + k);
            const float4 b = *(const float4*)(wr + k);
            s += (double)a.x * (double)b.x;
            s += (double)a.y * (double)b.y;
            s += (double)a.z * (double)b.z;
            s += (double)a.w * (double)b.w;
        }
        s += __shfl_xor(s, 1);
        s += __shfl_xor(s, 2);
        if (q == 0) sc[e] = s + (double)bias[e];
        __syncthreads();

        if (t == 0) {
            double v1 = -1e300, v2 = -1e300;
            int i1 = 0, i2 = 0;
            for (int j = 0; j < NE; ++j) {
                const double sv = sc[j];
                if (sv > v1)      { v2 = v1; i2 = i1; v1 = sv; i1 = j; }
                else if (sv > v2) { v2 = sv; i2 = j; }
            }
            const double ex = exp(v2 - v1);
            const double w1 = 1.0 / (1.0 + ex);
            const double w2 = ex * w1;
            const size_t g = (size_t)tok * 2;
            *(float2*)(out + g)                        = make_float2((float)w1, (float)w2);
            *(float2*)(out + (size_t)N_TOKENS * 2 + g) = make_float2((float)i1, (float)i2);
            atomicAdd(&ews_ref[i1], (float)w1);
            atomicAdd(&ews_ref[i2], (float)w2);
        }
        __syncthreads();
    }
}

__global__ void gate_bias(
    const float* __restrict__ bias,
    const float* __restrict__ target,
    const float* __restrict__ ws,
    float* __restrict__ out)
{
    const int e = threadIdx.x;   // 64 threads, one wave
    const float* partials = ws + 128;
    float v = ws[e];             // refined-token contribution
    for (int b = 0; b < NBLK; ++b) v += partials[(size_t)b * NE + e];
    float total = v;
    #pragma unroll
    for (int off = 32; off > 0; off >>= 1)
        total += __shfl_xor(total, off);
    const float nb = bias[e] + 0.001f * ((target[e] * total - v) / total);
    out[(size_t)N_TOKENS * 4 + e] = nb;
}

extern "C" void kernel_launch(void* const* d_in, const int* in_sizes, int n_in,
                              void* d_out, int out_size, void* d_ws, size_t ws_size,
                              hipStream_t stream) {
    const float* x      = (const float*)d_in[0];
    const float* w      = (const float*)d_in[1];
    const float* bias   = (const float*)d_in[2];
    const float* target = (const float*)d_in[3];
    float* out = (float*)d_out;
    float* ws  = (float*)d_ws;

    // zero ews_refine[64] + worklist counter
    hipMemsetAsync(ws, 0, 128 * sizeof(float), stream);
    gate_main  <<<NBLK, 256, 0, stream>>>(x, w, bias, out, ws);
    gate_refine<<<REFINE_BLOCKS, 256, 0, stream>>>(x, w, bias, out, ws);
    gate_bias  <<<1, 64, 0, stream>>>(bias, target, ws, out);
}

// Round 3
// 287.305 us; speedup vs baseline: 1.6723x; 1.6723x over previous
//
#include <hip/hip_runtime.h>
#include <math.h>

#define N_TOKENS 32768
#define DIM      4096
#define NE       64
#define TM       64              // tokens per block
#define BK       128             // K-chunk
#define NBLK     (N_TOKENS / TM) // 512 blocks
#define EPS_GAP  2e-3f
#define REFINE_BLOCKS 1024

// d_out layout (float32 elements):
//   [0, 65536)        weights  [N_TOKENS][2]
//   [65536, 131072)   indices  [N_TOKENS][2]  stored as float
//   [131072, 131136)  new_bias [64]
//
// d_ws layout (4-byte units):
//   [0, 64)              ews_refine[64]  (float, zeroed per call)
//   [64]                 worklist count  (uint, zeroed per call)
//   [128, 32896)         per-block expert partials [NBLK][NE] (float)
//   [32896, 65664)       worklist token ids (int)
//   [65664, ...)         W fragments: whi (512KB bf16) then wlo (512KB bf16)
#define WOFF 65664
#define WFRAG_ELEMS (512 * 512)   // 512 frags * 512 bf16 = 262144

typedef __bf16 bf16x4 __attribute__((ext_vector_type(4)));
typedef __bf16 bf16x8 __attribute__((ext_vector_type(8)));
typedef float  f32x16 __attribute__((ext_vector_type(16)));

// Convert W [64][4096] f32 -> fragment-ordered bf16 hi/lo.
// Fragment f = K16*2 + nt  (K16 = k/16, nt = expert-half):
//   element (f, lane, b) = W[nt*32 + (lane&31)][K16*16 + (lane>>5)*8 + b]
__global__ __launch_bounds__(256) void prep_w(
    const float* __restrict__ w, float* __restrict__ ws)
{
    __bf16* whi = (__bf16*)(ws + WOFF);
    __bf16* wlo = whi + WFRAG_ELEMS;
    const int tid  = blockIdx.x * 256 + threadIdx.x;  // 0..32767
    const int f    = tid >> 6, lane = tid & 63;
    const int nt   = f & 1,    K16  = f >> 1;
    const int e    = nt * 32 + (lane & 31);
    const int k    = K16 * 16 + (lane >> 5) * 8;
    const float4 a = *(const float4*)(w + (size_t)e * DIM + k);
    const float4 b = *(const float4*)(w + (size_t)e * DIM + k + 4);
    const float v[8] = {a.x, a.y, a.z, a.w, b.x, b.y, b.z, b.w};
    bf16x8 h, l;
    #pragma unroll
    for (int i = 0; i < 8; ++i) {
        h[i] = (__bf16)v[i];
        l[i] = (__bf16)(v[i] - (float)h[i]);
    }
    *(bf16x8*)(whi + (size_t)tid * 8) = h;
    *(bf16x8*)(wlo + (size_t)tid * 8) = l;
}

__device__ __forceinline__ void cvt_split(const float4 v, bf16x4& h, bf16x4& l) {
    h[0] = (__bf16)v.x; l[0] = (__bf16)(v.x - (float)h[0]);
    h[1] = (__bf16)v.y; l[1] = (__bf16)(v.y - (float)h[1]);
    h[2] = (__bf16)v.z; l[2] = (__bf16)(v.z - (float)h[2]);
    h[3] = (__bf16)v.w; l[3] = (__bf16)(v.w - (float)h[3]);
}

__global__ __launch_bounds__(256) void gate_main(
    const float* __restrict__ x,      // [N_TOKENS][DIM]
    const float* __restrict__ bias,   // [NE]
    float* __restrict__ out,
    float* __restrict__ ws)
{
    // LDS: x-tile bf16 hi at [0,16K), lo at [16K,32K). Row = token (64 rows
    // of 256B = 128 bf16), XOR-swizzled: byte ^= ((tok&7)<<4).
    __shared__ __align__(16) unsigned char smem[32768];
    __shared__ float part[NE];
    __shared__ float sbias[NE];

    unsigned* wl_count = (unsigned*)(ws + 64);
    float*    partials = ws + 128;
    int*      wl       = (int*)(ws + 32896);
    const __bf16* whi  = (const __bf16*)(ws + WOFF);
    const __bf16* wlo  = whi + WFRAG_ELEMS;

    const int t    = threadIdx.x;
    const int lane = t & 63;
    const int wave = t >> 6;
    const int mt   = wave >> 1;          // token half (0/1)
    const int nt   = wave & 1;           // expert half (0/1)
    const int tb   = blockIdx.x * TM;

    if (t < NE) { sbias[t] = bias[t]; part[t] = 0.f; }

    // staging mapping: thread t covers rows r = (t>>5) + 8j, k-quad q = t&31
    const int q     = t & 31;
    const int rbase = t >> 5;

    f32x16 acc0, acc1, acc2;
    #pragma unroll
    for (int i = 0; i < 16; ++i) { acc0[i] = 0.f; acc1[i] = 0.f; acc2[i] = 0.f; }

    float4 xv[8];
    #pragma unroll
    for (int j = 0; j < 8; ++j)
        xv[j] = *(const float4*)(x + (size_t)(tb + rbase + 8 * j) * DIM + q * 4);

    const int tok0  = mt * 32 + (lane & 31);   // A row this lane reads
    const int klane = lane >> 5;
    const int abase = tok0 * 256;
    const int aswz  = (tok0 & 7) << 4;

    for (int kc = 0; kc < DIM; kc += BK) {
        // ---- write staged regs to LDS as bf16 hi/lo (swizzled) ----
        #pragma unroll
        for (int j = 0; j < 8; ++j) {
            const int r = rbase + 8 * j;
            bf16x4 h, l;
            cvt_split(xv[j], h, l);
            const int off = r * 256 + ((q * 8) ^ ((r & 7) << 4));
            *(bf16x4*)(&smem[off])         = h;
            *(bf16x4*)(&smem[16384 + off]) = l;
        }
        __syncthreads();

        // ---- early-issue next chunk's x loads (hide HBM under MFMA) ----
        if (kc + BK < DIM) {
            #pragma unroll
            for (int j = 0; j < 8; ++j)
                xv[j] = *(const float4*)(x + (size_t)(tb + rbase + 8 * j) * DIM + kc + BK + q * 4);
        }

        // ---- compute: 8 k-steps of 16, 3 MFMA each ----
        const int K16c = kc >> 4;
        #pragma unroll
        for (int ks = 0; ks < 8; ++ks) {
            const int aoff = abase + ((ks * 32 + klane * 16) ^ aswz);
            const bf16x8 ah = *(const bf16x8*)(&smem[aoff]);
            const bf16x8 al = *(const bf16x8*)(&smem[16384 + aoff]);
            const size_t bidx = ((size_t)((K16c + ks) * 2 + nt) * 64 + lane) * 8;
            const bf16x8 bh = *(const bf16x8*)(whi + bidx);
            const bf16x8 bl = *(const bf16x8*)(wlo + bidx);
            acc0 = __builtin_amdgcn_mfma_f32_32x32x16_bf16(ah, bh, acc0, 0, 0, 0);
            acc1 = __builtin_amdgcn_mfma_f32_32x32x16_bf16(al, bh, acc1, 0, 0, 0);
            acc2 = __builtin_amdgcn_mfma_f32_32x32x16_bf16(ah, bl, acc2, 0, 0, 0);
        }
        __syncthreads();
    }

    // ---- epilogue: scores -> LDS sc[64][68] f32 (reuse smem) ----
    float* sc = (float*)smem;
    const int e = nt * 32 + (lane & 31);
    #pragma unroll
    for (int r = 0; r < 16; ++r) {
        const int tok = mt * 32 + (r & 3) + 8 * (r >> 2) + 4 * (lane >> 5);
        sc[tok * 68 + e] = acc0[r] + acc1[r] + acc2[r];
    }
    __syncthreads();

    if (t < TM) {
        const int tok = t;
        float v1 = -3e38f, v2 = -3e38f, v3 = -3e38f;
        int   i1 = 0,      i2 = 0;
        #pragma unroll 8
        for (int ei = 0; ei < NE; ++ei) {
            const float s = sc[tok * 68 + ei] + sbias[ei];
            if (s > v1)      { v3 = v2; v2 = v1; i2 = i1; v1 = s; i1 = ei; }
            else if (s > v2) { v3 = v2; v2 = s;  i2 = ei; }
            else if (s > v3) { v3 = s; }
        }
        const bool risky = (v1 - v2 < EPS_GAP) || (v2 - v3 < EPS_GAP);
        if (risky) {
            const int pos = (int)atomicAdd(wl_count, 1u);
            wl[pos] = tb + tok;                  // refined later in fp64
        } else {
            const float ex = expf(v2 - v1);      // <= 1
            const float w1 = 1.f / (1.f + ex);
            const float w2 = ex * w1;
            const size_t g = (size_t)(tb + tok) * 2;
            *(float2*)(out + g)                        = make_float2(w1, w2);
            *(float2*)(out + (size_t)N_TOKENS * 2 + g) = make_float2((float)i1, (float)i2);
            atomicAdd(&part[i1], w1);
            atomicAdd(&part[i2], w2);
        }
    }
    __syncthreads();

    if (t < NE) partials[(size_t)blockIdx.x * NE + t] = part[t];
}

// fp64 re-score of near-tie tokens: exact ordering vs the true scores.
__global__ __launch_bounds__(256) void gate_refine(
    const float* __restrict__ x,
    const float* __restrict__ w,
    const float* __restrict__ bias,
    float* __restrict__ out,
    float* __restrict__ ws)
{
    float*          ews_ref  = ws;
    const unsigned* wl_count = (const unsigned*)(ws + 64);
    const int*      wl       = (const int*)(ws + 32896);

    const int t = threadIdx.x;
    const int e = t >> 2;        // expert 0..63
    const int q = t & 3;         // quarter of K
    __shared__ double sc[NE];

    const unsigned count = *wl_count;
    for (unsigned it = blockIdx.x; it < count; it += gridDim.x) {
        const int tok = wl[it];
        const float* xr = x + (size_t)tok * DIM;
        const float* wr = w + (size_t)e * DIM;
        double s = 0.0;
        const int k0 = q * (DIM / 4), k1 = k0 + DIM / 4;
        for (int k = k0; k < k1; k += 4) {
            const float4 a = *(const float4*)(xr + k);
            const float4 b = *(const float4*)(wr + k);
            s += (double)a.x * (double)b.x;
            s += (double)a.y * (double)b.y;
            s += (double)a.z * (double)b.z;
            s += (double)a.w * (double)b.w;
        }
        s += __shfl_xor(s, 1);
        s += __shfl_xor(s, 2);
        if (q == 0) sc[e] = s + (double)bias[e];
        __syncthreads();

        if (t == 0) {
            double v1 = -1e300, v2 = -1e300;
            int i1 = 0, i2 = 0;
            for (int j = 0; j < NE; ++j) {
                const double sv = sc[j];
                if (sv > v1)      { v2 = v1; i2 = i1; v1 = sv; i1 = j; }
                else if (sv > v2) { v2 = sv; i2 = j; }
            }
            const double ex = exp(v2 - v1);
            const double w1 = 1.0 / (1.0 + ex);
            const double w2 = ex * w1;
            const size_t g = (size_t)tok * 2;
            *(float2*)(out + g)                        = make_float2((float)w1, (float)w2);
            *(float2*)(out + (size_t)N_TOKENS * 2 + g) = make_float2((float)i1, (float)i2);
            atomicAdd(&ews_ref[i1], (float)w1);
            atomicAdd(&ews_ref[i2], (float)w2);
        }
        __syncthreads();
    }
}

__global__ void gate_bias(
    const float* __restrict__ bias,
    const float* __restrict__ target,
    const float* __restrict__ ws,
    float* __restrict__ out)
{
    const int e = threadIdx.x;   // 64 threads, one wave
    const float* partials = ws + 128;
    float v = ws[e];             // refined-token contribution
    for (int b = 0; b < NBLK; ++b) v += partials[(size_t)b * NE + e];
    float total = v;
    #pragma unroll
    for (int off = 32; off > 0; off >>= 1)
        total += __shfl_xor(total, off);
    const float nb = bias[e] + 0.001f * ((target[e] * total - v) / total);
    out[(size_t)N_TOKENS * 4 + e] = nb;
}

extern "C" void kernel_launch(void* const* d_in, const int* in_sizes, int n_in,
                              void* d_out, int out_size, void* d_ws, size_t ws_size,
                              hipStream_t stream) {
    const float* x      = (const float*)d_in[0];
    const float* w      = (const float*)d_in[1];
    const float* bias   = (const float*)d_in[2];
    const float* target = (const float*)d_in[3];
    float* out = (float*)d_out;
    float* ws  = (float*)d_ws;

    hipMemsetAsync(ws, 0, 128 * sizeof(float), stream);   // ews_ref + wl_count
    prep_w     <<<128, 256, 0, stream>>>(w, ws);
    gate_main  <<<NBLK, 256, 0, stream>>>(x, bias, out, ws);
    gate_refine<<<REFINE_BLOCKS, 256, 0, stream>>>(x, w, bias, out, ws);
    gate_bias  <<<1, 64, 0, stream>>>(bias, target, ws, out);
}

// Round 4
// 281.446 us; speedup vs baseline: 1.7071x; 1.0208x over previous
//
#include <hip/hip_runtime.h>
#include <math.h>

#define N_TOKENS 32768
#define DIM      4096
#define NE       64
#define TM       64              // tokens per block
#define BK       128             // K-chunk
#define KHALF    (DIM / 2)       // 2048
#define NBLK_MAIN (N_TOKENS / TM * 2)   // 1024 (x2 for K-split)
#define NBLK_POST (N_TOKENS / 256)      // 128
#define EPS_GAP  2e-3f
#define REFINE_BLOCKS 1024

// d_out layout (float32 elements):
//   [0, 65536)        weights  [N_TOKENS][2]
//   [65536, 131072)   indices  [N_TOKENS][2]  stored as float
//   [131072, 131136)  new_bias [64]
//
// d_ws layout (4-byte units):
//   [0, 64)              ews_refine[64]  (float, zeroed per call)
//   [64]                 worklist count  (uint, zeroed per call)
//   [128, 8320)          per-post-block expert partials [128][64] (float)
//   [16384, 49152)       worklist token ids (int)
//   [65664, 327808)      W fragments: whi then wlo (bf16, 512KB each)
//   [524288, 4718592)    partial scores psc[2][N_TOKENS][64] (f32, 16.8MB)
#define WOFF     65664
#define WL_OFF   16384
#define PART_OFF 128
#define PSC_OFF  524288
#define WFRAG_ELEMS (512 * 512)   // 262144 bf16 per plane

typedef __bf16 bf16x4 __attribute__((ext_vector_type(4)));
typedef __bf16 bf16x8 __attribute__((ext_vector_type(8)));
typedef float  f32x16 __attribute__((ext_vector_type(16)));

// Convert W [64][4096] f32 -> fragment-ordered bf16 hi/lo.
// Fragment f = K16*2 + nt:  element (f, lane, b) =
//   W[nt*32 + (lane&31)][K16*16 + (lane>>5)*8 + b]
__global__ __launch_bounds__(256) void prep_w(
    const float* __restrict__ w, float* __restrict__ ws)
{
    __bf16* whi = (__bf16*)(ws + WOFF);
    __bf16* wlo = whi + WFRAG_ELEMS;
    const int tid  = blockIdx.x * 256 + threadIdx.x;  // 0..32767
    const int f    = tid >> 6, lane = tid & 63;
    const int nt   = f & 1,    K16  = f >> 1;
    const int e    = nt * 32 + (lane & 31);
    const int k    = K16 * 16 + (lane >> 5) * 8;
    const float4 a = *(const float4*)(w + (size_t)e * DIM + k);
    const float4 b = *(const float4*)(w + (size_t)e * DIM + k + 4);
    const float v[8] = {a.x, a.y, a.z, a.w, b.x, b.y, b.z, b.w};
    bf16x8 h, l;
    #pragma unroll
    for (int i = 0; i < 8; ++i) {
        h[i] = (__bf16)v[i];
        l[i] = (__bf16)(v[i] - (float)h[i]);
    }
    *(bf16x8*)(whi + (size_t)tid * 8) = h;
    *(bf16x8*)(wlo + (size_t)tid * 8) = l;
}

__device__ __forceinline__ void cvt_split(const float4 v, bf16x4& h, bf16x4& l) {
    h[0] = (__bf16)v.x; l[0] = (__bf16)(v.x - (float)h[0]);
    h[1] = (__bf16)v.y; l[1] = (__bf16)(v.y - (float)h[1]);
    h[2] = (__bf16)v.z; l[2] = (__bf16)(v.z - (float)h[2]);
    h[3] = (__bf16)v.w; l[3] = (__bf16)(v.w - (float)h[3]);
}

// Split-K GEMM: block b handles tokens [tb, tb+64), K-half kh = b&1.
// Writes partial scores psc[kh][tok][e].
__global__ __launch_bounds__(256, 4) void gate_main(
    const float* __restrict__ x,      // [N_TOKENS][DIM]
    float* __restrict__ ws)
{
    // LDS: x-tile bf16 hi [0,16K), lo [16K,32K). Row = token (256B = 128 bf16),
    // XOR-swizzled: byte ^= ((tok&7)<<4).
    __shared__ __align__(16) unsigned char smem[32768];

    const __bf16* whi = (const __bf16*)(ws + WOFF);
    const __bf16* wlo = whi + WFRAG_ELEMS;
    float*        psc = ws + PSC_OFF;

    const int t    = threadIdx.x;
    const int lane = t & 63;
    const int wave = t >> 6;
    const int mt   = wave >> 1;          // token half (0/1)
    const int nt   = wave & 1;           // expert half (0/1)
    const int kh   = blockIdx.x & 1;     // K half
    const int tb   = (blockIdx.x >> 1) * TM;
    const int kbeg = kh * KHALF;

    // staging: thread t covers rows r = (t>>5) + 8j, k-quad q = t&31
    const int q     = t & 31;
    const int rbase = t >> 5;

    f32x16 acc0, acc12;
    #pragma unroll
    for (int i = 0; i < 16; ++i) { acc0[i] = 0.f; acc12[i] = 0.f; }

    float4 xv[8];
    #pragma unroll
    for (int j = 0; j < 8; ++j)
        xv[j] = *(const float4*)(x + (size_t)(tb + rbase + 8 * j) * DIM + kbeg + q * 4);

    const int tok0  = mt * 32 + (lane & 31);   // A row this lane reads
    const int klane = lane >> 5;
    const int abase = tok0 * 256;
    const int aswz  = (tok0 & 7) << 4;

    for (int kc = kbeg; kc < kbeg + KHALF; kc += BK) {
        // ---- write staged regs to LDS as bf16 hi/lo (swizzled) ----
        #pragma unroll
        for (int j = 0; j < 8; ++j) {
            const int r = rbase + 8 * j;
            bf16x4 h, l;
            cvt_split(xv[j], h, l);
            const int off = r * 256 + ((q * 8) ^ ((r & 7) << 4));
            *(bf16x4*)(&smem[off])         = h;
            *(bf16x4*)(&smem[16384 + off]) = l;
        }
        __syncthreads();

        // ---- early-issue next chunk's x loads ----
        if (kc + BK < kbeg + KHALF) {
            #pragma unroll
            for (int j = 0; j < 8; ++j)
                xv[j] = *(const float4*)(x + (size_t)(tb + rbase + 8 * j) * DIM + kc + BK + q * 4);
        }

        // ---- compute: 8 k-steps of 16, 3 MFMA each ----
        const int K16c = kc >> 4;
        #pragma unroll
        for (int ks = 0; ks < 8; ++ks) {
            const int aoff = abase + ((ks * 32 + klane * 16) ^ aswz);
            const bf16x8 ah = *(const bf16x8*)(&smem[aoff]);
            const bf16x8 al = *(const bf16x8*)(&smem[16384 + aoff]);
            const size_t bidx = ((size_t)((K16c + ks) * 2 + nt) * 64 + lane) * 8;
            const bf16x8 bh = *(const bf16x8*)(whi + bidx);
            const bf16x8 bl = *(const bf16x8*)(wlo + bidx);
            acc0  = __builtin_amdgcn_mfma_f32_32x32x16_bf16(ah, bh, acc0,  0, 0, 0);
            acc12 = __builtin_amdgcn_mfma_f32_32x32x16_bf16(al, bh, acc12, 0, 0, 0);
            acc12 = __builtin_amdgcn_mfma_f32_32x32x16_bf16(ah, bl, acc12, 0, 0, 0);
        }
        __syncthreads();
    }

    // ---- write partial scores (C/D layout: col=lane&31, row=(r&3)+8*(r>>2)+4*(lane>>5)) ----
    const int e = nt * 32 + (lane & 31);
    float* base = psc + (size_t)kh * N_TOKENS * NE;
    #pragma unroll
    for (int r = 0; r < 16; ++r) {
        const int tok = mt * 32 + (r & 3) + 8 * (r >> 2) + 4 * (lane >> 5);
        base[(size_t)(tb + tok) * NE + e] = acc0[r] + acc12[r];
    }
}

// Sum K-halves + bias, top-3 scan, risky-flag or write outputs; expert partials.
__global__ __launch_bounds__(256) void gate_post(
    const float* __restrict__ bias,
    float* __restrict__ out,
    float* __restrict__ ws)
{
    __shared__ float sbias[NE];
    __shared__ float part[NE];
    unsigned* wl_count = (unsigned*)(ws + 64);
    float*    partials = ws + PART_OFF;
    int*      wl       = (int*)(ws + WL_OFF);
    const float* psc   = ws + PSC_OFF;

    const int t = threadIdx.x;
    if (t < NE) { sbias[t] = bias[t]; part[t] = 0.f; }
    __syncthreads();

    const int tok = blockIdx.x * 256 + t;
    const float* p0 = psc + (size_t)tok * NE;
    const float* p1 = psc + (size_t)N_TOKENS * NE + (size_t)tok * NE;

    float v1 = -3e38f, v2 = -3e38f, v3 = -3e38f;
    int   i1 = 0,      i2 = 0;
    #pragma unroll
    for (int g = 0; g < 16; ++g) {
        const float4 a = *(const float4*)(p0 + g * 4);
        const float4 b = *(const float4*)(p1 + g * 4);
        float s[4] = {a.x + b.x, a.y + b.y, a.z + b.z, a.w + b.w};
        #pragma unroll
        for (int j = 0; j < 4; ++j) {
            const float sv = s[j] + sbias[g * 4 + j];
            const int   e  = g * 4 + j;
            if (sv > v1)      { v3 = v2; v2 = v1; i2 = i1; v1 = sv; i1 = e; }
            else if (sv > v2) { v3 = v2; v2 = sv; i2 = e; }
            else if (sv > v3) { v3 = sv; }
        }
    }
    const bool risky = (v1 - v2 < EPS_GAP) || (v2 - v3 < EPS_GAP);
    if (risky) {
        const int pos = (int)atomicAdd(wl_count, 1u);
        wl[pos] = tok;                       // refined later in fp64
    } else {
        const float ex = expf(v2 - v1);      // <= 1
        const float w1 = 1.f / (1.f + ex);
        const float w2 = ex * w1;
        const size_t g = (size_t)tok * 2;
        *(float2*)(out + g)                        = make_float2(w1, w2);
        *(float2*)(out + (size_t)N_TOKENS * 2 + g) = make_float2((float)i1, (float)i2);
        atomicAdd(&part[i1], w1);
        atomicAdd(&part[i2], w2);
    }
    __syncthreads();
    if (t < NE) partials[(size_t)blockIdx.x * NE + t] = part[t];
}

// fp64 re-score of near-tie tokens: exact ordering vs the true scores.
__global__ __launch_bounds__(256) void gate_refine(
    const float* __restrict__ x,
    const float* __restrict__ w,
    const float* __restrict__ bias,
    float* __restrict__ out,
    float* __restrict__ ws)
{
    float*          ews_ref  = ws;
    const unsigned* wl_count = (const unsigned*)(ws + 64);
    const int*      wl       = (const int*)(ws + WL_OFF);

    const int t = threadIdx.x;
    const int e = t >> 2;        // expert 0..63
    const int q = t & 3;         // quarter of K
    __shared__ double sc[NE];

    const unsigned count = *wl_count;
    for (unsigned it = blockIdx.x; it < count; it += gridDim.x) {
        const int tok = wl[it];
        const float* xr = x + (size_t)tok * DIM;
        const float* wr = w + (size_t)e * DIM;
        double s = 0.0;
        const int k0 = q * (DIM / 4), k1 = k0 + DIM / 4;
        for (int k = k0; k < k1; k += 4) {
            const float4 a = *(const float4*)(xr + k);
            const float4 b = *(const float4*)(wr + k);
            s += (double)a.x * (double)b.x;
            s += (double)a.y * (double)b.y;
            s += (double)a.z * (double)b.z;
            s += (double)a.w * (double)b.w;
        }
        s += __shfl_xor(s, 1);
        s += __shfl_xor(s, 2);
        if (q == 0) sc[e] = s + (double)bias[e];
        __syncthreads();

        if (t == 0) {
            double v1 = -1e300, v2 = -1e300;
            int i1 = 0, i2 = 0;
            for (int j = 0; j < NE; ++j) {
                const double sv = sc[j];
                if (sv > v1)      { v2 = v1; i2 = i1; v1 = sv; i1 = j; }
                else if (sv > v2) { v2 = sv; i2 = j; }
            }
            const double ex = exp(v2 - v1);
            const double w1 = 1.0 / (1.0 + ex);
            const double w2 = ex * w1;
            const size_t g = (size_t)tok * 2;
            *(float2*)(out + g)                        = make_float2((float)w1, (float)w2);
            *(float2*)(out + (size_t)N_TOKENS * 2 + g) = make_float2((float)i1, (float)i2);
            atomicAdd(&ews_ref[i1], (float)w1);
            atomicAdd(&ews_ref[i2], (float)w2);
        }
        __syncthreads();
    }
}

__global__ void gate_bias(
    const float* __restrict__ bias,
    const float* __restrict__ target,
    const float* __restrict__ ws,
    float* __restrict__ out)
{
    const int e = threadIdx.x;   // 64 threads, one wave
    const float* partials = ws + PART_OFF;
    float v = ws[e];             // refined-token contribution
    for (int b = 0; b < NBLK_POST; ++b) v += partials[(size_t)b * NE + e];
    float total = v;
    #pragma unroll
    for (int off = 32; off > 0; off >>= 1)
        total += __shfl_xor(total, off);
    const float nb = bias[e] + 0.001f * ((target[e] * total - v) / total);
    out[(size_t)N_TOKENS * 4 + e] = nb;
}

extern "C" void kernel_launch(void* const* d_in, const int* in_sizes, int n_in,
                              void* d_out, int out_size, void* d_ws, size_t ws_size,
                              hipStream_t stream) {
    const float* x      = (const float*)d_in[0];
    const float* w      = (const float*)d_in[1];
    const float* bias   = (const float*)d_in[2];
    const float* target = (const float*)d_in[3];
    float* out = (float*)d_out;
    float* ws  = (float*)d_ws;

    hipMemsetAsync(ws, 0, 128 * sizeof(float), stream);   // ews_ref + wl_count
    prep_w     <<<128, 256, 0, stream>>>(w, ws);
    gate_main  <<<NBLK_MAIN, 256, 0, stream>>>(x, ws);
    gate_post  <<<NBLK_POST, 256, 0, stream>>>(bias, out, ws);
    gate_refine<<<REFINE_BLOCKS, 256, 0, stream>>>(x, w, bias, out, ws);
    gate_bias  <<<1, 64, 0, stream>>>(bias, target, ws, out);
}